// Round 8
// baseline (141.839 us; speedup 1.0000x reference)
//
#include <hip/hip_runtime.h>
#include <hip/hip_bf16.h>
#include <math.h>

// DCNv2 forward, fully fused, barrier-free main loop: aux conv (MFMA -> LDS),
// then deformable sampling packs bilinear results DIRECTLY into MFMA
// A-fragments (D = V·W^T), weights as B-fragments. No LDS val tile, no
// per-tap barriers. Input staged once as NHWC bf16.
// x [4,64,192,192] f32; w_off [18,64,3,3]; b_off[18]; w_mod [9,64,3,3]; b_mod[9];
// w [64,64,3,3]; b[64]; out [4,64,192,192] f32.

#define NB   4
#define CIN  64
#define COUT 64
#define HH   192
#define WW   192
#define HW   (HH*WW)

typedef __attribute__((ext_vector_type(4))) float f32x4;
typedef __attribute__((ext_vector_type(2))) float f32x2;
typedef __attribute__((ext_vector_type(8))) short bf16x8;
typedef __attribute__((ext_vector_type(4))) unsigned int u32x4;

__device__ __forceinline__ int iclamp(int v, int lo, int hi) {
    return v < lo ? lo : (v > hi ? hi : v);
}
__device__ __forceinline__ unsigned short bf16bits(float f) {
    __hip_bfloat16 h = __float2bfloat16(f);
    return *reinterpret_cast<unsigned short*>(&h);
}
// unpack a u32 holding 2 bf16 into float2: lo = u<<16, hi = u & 0xffff0000
__device__ __forceinline__ f32x2 unpk2(unsigned int u) {
    union { unsigned int i; float f; } lo, hi;
    lo.i = u << 16;
    hi.i = u & 0xffff0000u;
    return (f32x2){lo.f, hi.f};
}
#if __has_builtin(__builtin_elementwise_fma)
__device__ __forceinline__ f32x2 pfma(f32x2 a, f32x2 b, f32x2 c) {
    return __builtin_elementwise_fma(a, b, c);
}
#else
__device__ __forceinline__ f32x2 pfma(f32x2 a, f32x2 b, f32x2 c) {
    return (f32x2){fmaf(a.x, b.x, c.x), fmaf(a.y, b.y, c.y)};
}
#endif

// ---------------------------------------------------------------------------
// Kernel A: x f32 NCHW -> xt bf16 NHWC (128 B per pixel).
// ---------------------------------------------------------------------------
__global__ __launch_bounds__(256) void to_nhwc(
        const float* __restrict__ x, unsigned short* __restrict__ xt) {
    int n  = blockIdx.y;
    int px = blockIdx.x * 256 + threadIdx.x;     // 0..HW-1
    const float* xn = x + (size_t)n * CIN * HW + px;
    union { unsigned short us[64]; u32x4 q[8]; } pk;
#pragma unroll
    for (int c = 0; c < 64; c++) pk.us[c] = bf16bits(xn[c * HW]);
    u32x4* dst = (u32x4*)(xt + ((size_t)n * HW + px) * 64);
#pragma unroll
    for (int i = 0; i < 8; i++) dst[i] = pk.q[i];
}

// ---------------------------------------------------------------------------
// Kernel 0: weight repack into MFMA fragment order (bf16).
//  wfrag (main): idx = (((k*4+nf)*2+kc)*64 + l)*8 + j
//        holds W[o = nf*16 + (l&15)][c = kc*32 + (l>>4)*8 + j]
//        (same lane layout serves as B-fragment: n = l&15, k = (l>>4)*8+j)
//  wauxf (aux, 32 out-ch padded from 27): idx = ((k*4 + ga*2 + kc)*64 + l)*8 + j
//  baux  f32[32]: b_off | b_mod | 0
// ---------------------------------------------------------------------------
__global__ __launch_bounds__(256) void prep_weights(
        const float* __restrict__ w, const float* __restrict__ w_off,
        const float* __restrict__ w_mod, const float* __restrict__ b_off,
        const float* __restrict__ b_mod, __hip_bfloat16* __restrict__ wfrag,
        __hip_bfloat16* __restrict__ wauxf, float* __restrict__ baux) {
    int idx = blockIdx.x * 256 + threadIdx.x;
    if (idx < 36864) {
        int j    = idx & 7;
        int lane = (idx >> 3) & 63;
        int kc   = (idx >> 9) & 1;
        int g    = (idx >> 10) & 3;
        int k    = idx >> 12;
        int o = g * 16 + (lane & 15);
        int c = kc * 32 + (lane >> 4) * 8 + j;
        wfrag[idx] = __float2bfloat16(w[(o * 64 + c) * 9 + k]);
    }
    if (idx < 18432) {
        int j    = idx & 7;
        int lane = (idx >> 3) & 63;
        int kc   = (idx >> 9) & 1;
        int ga   = (idx >> 10) & 1;
        int k    = idx >> 11;
        int o = ga * 16 + (lane & 15);
        int c = kc * 32 + (lane >> 4) * 8 + j;
        float v = 0.f;
        if (o < 18)      v = w_off[(o * 64 + c) * 9 + k];
        else if (o < 27) v = w_mod[((o - 18) * 64 + c) * 9 + k];
        wauxf[idx] = __float2bfloat16(v);
    }
    if (idx < 32) {
        float v = 0.f;
        if (idx < 18)      v = b_off[idx];
        else if (idx < 27) v = b_mod[idx - 18];
        baux[idx] = v;
    }
}

// ---------------------------------------------------------------------------
// Fused kernel.
// Phase A: aux conv via MFMA -> oml[32][65] in LDS (one barrier after).
// Phase B: per tap, lane (pixel=l&15 within wave, chunk=l>>4) gathers its
// pixel's 4 bilinear corners (2 x b128 each), combines with packed f32, and
// packs straight into the two A-fragments (kc0/kc1); 8 MFMA vs weight
// B-fragments. No LDS traffic, no barriers -> waves fully independent.
// ---------------------------------------------------------------------------
__global__ __launch_bounds__(256, 4) void dcn_fused(
        const unsigned short* __restrict__ xt,
        const __hip_bfloat16* __restrict__ wfrag,
        const __hip_bfloat16* __restrict__ wauxf,
        const float* __restrict__ baux,
        const float* __restrict__ bias,
        float* __restrict__ out) {
    __shared__ float oml[32][65];                 // aux results (8.3 KB)

    int tid = threadIdx.x;
    int l   = tid & 63;
    int g   = __builtin_amdgcn_readfirstlane(tid >> 6);

    int id = blockIdx.x;                        // 0..2303
    int sw = (id & 7) * 288 + (id >> 3);        // bijective XCD swizzle
    int n  = sw / 576;
    int r  = sw % 576;
    int ho = r / 3;
    int wx = r % 3;
    int wobase = wx * 64;

    const char* xb = (const char*)xt + (size_t)n * HW * 128;

    // ================= Phase A: aux conv for this tile =================
    {
        f32x4 aacc[2];
        aacc[0] = (f32x4){0.f, 0.f, 0.f, 0.f};
        aacc[1] = (f32x4){0.f, 0.f, 0.f, 0.f};
        const bf16x8 zero8 = (bf16x8){0, 0, 0, 0, 0, 0, 0, 0};
        int pa  = g * 16 + (l & 15);            // this lane's pixel
        int cba = (l >> 4) * 16;                // 8-ch chunk byte offset

#pragma unroll 1
        for (int k = 0; k < 9; k++) {
            int ky = k / 3, kx = k - 3 * (k / 3);
            int ys = ho + ky - 1;
            if ((unsigned)ys >= (unsigned)HH) continue;   // uniform row skip
            int xs = wobase + pa + kx - 1;
            bool ok = (unsigned)xs < (unsigned)WW;
            int xsc = iclamp(xs, 0, WW - 1);
            const char* pp = xb + ((size_t)ys * WW + xsc) * 128;
            const bf16x8* wa = ((const bf16x8*)wauxf) + (k * 4) * 64 + l;
#pragma unroll
            for (int kc = 0; kc < 2; kc++) {
                bf16x8 bv = *(const bf16x8*)(pp + kc * 64 + cba);
                if (!ok) bv = zero8;
                bf16x8 a0 = wa[(kc)     * 64];      // o 0..15
                bf16x8 a1 = wa[(2 + kc) * 64];      // o 16..31
                aacc[0] = __builtin_amdgcn_mfma_f32_16x16x32_bf16(a0, bv, aacc[0], 0, 0, 0);
                aacc[1] = __builtin_amdgcn_mfma_f32_16x16x32_bf16(a1, bv, aacc[1], 0, 0, 0);
            }
        }
#pragma unroll
        for (int h = 0; h < 2; h++) {
#pragma unroll
            for (int rr = 0; rr < 4; rr++) {
                int o = h * 16 + (l >> 4) * 4 + rr;
                float v = aacc[h][rr] + baux[o];
                if (o >= 18) v = 2.f / (1.f + expf(-v));
                oml[o][pa] = v;
            }
        }
    }
    __syncthreads();   // the only block-wide barrier

    // ================= Phase B: deform sample + main conv =================
    f32x4 acc[4];
#pragma unroll
    for (int nf = 0; nf < 4; nf++) acc[nf] = (f32x4){0.f, 0.f, 0.f, 0.f};

    int p_loc = l & 15;             // pixel within wave's 16 (M-row)
    int chunk = l >> 4;             // K-chunk 0..3
    int p     = g * 16 + p_loc;     // pixel in tile
    int wox   = wobase + p;         // global wo of this pixel
    int cb0   = chunk * 16;         // kc0 byte offset within pixel line

#pragma unroll 1
    for (int k = 0; k < 9; k++) {
        // --- weight B-fragments for this tap (L1-broadcast, 8 x b128) ---
        const bf16x8* wfk = ((const bf16x8*)wfrag) + (k * 8) * 64 + l;
        bf16x8 wB[4][2];
#pragma unroll
        for (int nf = 0; nf < 4; nf++) {
            wB[nf][0] = wfk[(nf * 2)     * 64];
            wB[nf][1] = wfk[(nf * 2 + 1) * 64];
        }

        // --- geometry (4 chunk-lanes share one pixel) ---
        int ky = k / 3, kx = k - 3 * (k / 3);
        float offy = oml[2 * k][p];
        float offx = oml[2 * k + 1][p];
        float mm   = oml[18 + k][p];
        float py  = offy + (float)(ho - 1 + ky);
        float pxf = offx + (float)(wox - 1 + kx);
        float y0f = floorf(py), x0f = floorf(pxf);
        float ly = py - y0f, lx = pxf - x0f;
        int y0 = (int)y0f, x0 = (int)x0f;
        int y1 = y0 + 1, x1 = x0 + 1;
        bool y0ok = (unsigned)y0 < (unsigned)HH, y1ok = (unsigned)y1 < (unsigned)HH;
        bool x0ok = (unsigned)x0 < (unsigned)WW, x1ok = (unsigned)x1 < (unsigned)WW;
        float wt0 = (y0ok && x0ok) ? mm * (1.f - ly) * (1.f - lx) : 0.f;
        float wt1 = (y0ok && x1ok) ? mm * (1.f - ly) * lx         : 0.f;
        float wt2 = (y1ok && x0ok) ? mm * ly * (1.f - lx)         : 0.f;
        float wt3 = (y1ok && x1ok) ? mm * ly * lx                 : 0.f;
        int y0c = iclamp(y0, 0, HH - 1), y1c = iclamp(y1, 0, HH - 1);
        int x0c = iclamp(x0, 0, WW - 1), x1c = iclamp(x1, 0, WW - 1);

        // --- 8 gather b128: per corner, kc0 chunk and kc1 chunk ---
        const char* c00 = xb + ((size_t)y0c * WW + x0c) * 128 + cb0;
        const char* c01 = xb + ((size_t)y0c * WW + x1c) * 128 + cb0;
        const char* c10 = xb + ((size_t)y1c * WW + x0c) * 128 + cb0;
        const char* c11 = xb + ((size_t)y1c * WW + x1c) * 128 + cb0;
        u32x4 qa0 = *(const u32x4*)(c00);
        u32x4 qb0 = *(const u32x4*)(c00 + 64);
        u32x4 qa1 = *(const u32x4*)(c01);
        u32x4 qb1 = *(const u32x4*)(c01 + 64);
        u32x4 qa2 = *(const u32x4*)(c10);
        u32x4 qb2 = *(const u32x4*)(c10 + 64);
        u32x4 qa3 = *(const u32x4*)(c11);
        u32x4 qb3 = *(const u32x4*)(c11 + 64);

        // --- packed-f32 bilinear -> A-fragments (registers, no LDS) ---
        f32x2 w0 = (f32x2){wt0, wt0};
        f32x2 w1 = (f32x2){wt1, wt1};
        f32x2 w2 = (f32x2){wt2, wt2};
        f32x2 w3 = (f32x2){wt3, wt3};
        union { unsigned short us[8]; u32x4 v; bf16x8 h; } fA0, fA1;
#pragma unroll
        for (int j = 0; j < 4; j++) {
            f32x2 v = unpk2(qa0[j]) * w0;
            v = pfma(unpk2(qa1[j]), w1, v);
            v = pfma(unpk2(qa2[j]), w2, v);
            v = pfma(unpk2(qa3[j]), w3, v);
            fA0.us[2 * j]     = bf16bits(v.x);
            fA0.us[2 * j + 1] = bf16bits(v.y);
            f32x2 u = unpk2(qb0[j]) * w0;
            u = pfma(unpk2(qb1[j]), w1, u);
            u = pfma(unpk2(qb2[j]), w2, u);
            u = pfma(unpk2(qb3[j]), w3, u);
            fA1.us[2 * j]     = bf16bits(u.x);
            fA1.us[2 * j + 1] = bf16bits(u.y);
        }

        // --- 8 MFMA: D[p][o] += V(16x32) * W^T(32x16) per o-tile ---
#pragma unroll
        for (int nf = 0; nf < 4; nf++) {
            acc[nf] = __builtin_amdgcn_mfma_f32_16x16x32_bf16(fA0.h, wB[nf][0], acc[nf], 0, 0, 0);
            acc[nf] = __builtin_amdgcn_mfma_f32_16x16x32_bf16(fA1.h, wB[nf][1], acc[nf], 0, 0, 0);
        }
    }

    // epilogue: D map row=(l>>4)*4+rr = pixel-in-wave, col=l&15 = o-in-tile
#pragma unroll
    for (int nf = 0; nf < 4; nf++) {
        int o = nf * 16 + p_loc;
        float bo = bias[o];
        int wo = wobase + g * 16 + chunk * 4;
        float* op = out + (((size_t)n * COUT + o) * HH + ho) * WW + wo;
#pragma unroll
        for (int rr = 0; rr < 4; rr++) {
            float v = acc[nf][rr] + bo;
            op[rr] = fmaxf(v, 0.f);
        }
    }
}

// ---------------------------------------------------------------------------
extern "C" void kernel_launch(void* const* d_in, const int* in_sizes, int n_in,
                              void* d_out, int out_size, void* d_ws, size_t ws_size,
                              hipStream_t stream) {
    const float* x     = (const float*)d_in[0];
    const float* w_off = (const float*)d_in[1];
    const float* b_off = (const float*)d_in[2];
    const float* w_mod = (const float*)d_in[3];
    const float* b_mod = (const float*)d_in[4];
    const float* w     = (const float*)d_in[5];
    const float* b     = (const float*)d_in[6];
    float* out = (float*)d_out;

    // ws layout: wfrag bf16[36864] | wauxf bf16[18432] | baux f32[32] |
    //            xt bf16 NHWC [4*HW*64]                       (~19 MB)
    __hip_bfloat16* wfrag = (__hip_bfloat16*)d_ws;
    __hip_bfloat16* wauxf = wfrag + 36864;
    float* baux = (float*)(wauxf + 18432);
    unsigned short* xt = (unsigned short*)(baux + 32);

    to_nhwc<<<dim3(144, NB), dim3(256), 0, stream>>>(x, xt);
    prep_weights<<<dim3(144), dim3(256), 0, stream>>>(w, w_off, w_mod, b_off,
                                                      b_mod, wfrag, wauxf, baux);
    dcn_fused<<<dim3(2304), dim3(256), 0, stream>>>(xt, wfrag, wauxf, baux, b, out);
}